// Round 1
// baseline (753.575 us; speedup 1.0000x reference)
//
#include <hip/hip_runtime.h>
#include <stdint.h>

#define N_V 100000
#define N_E 200000
#define NNZ 800000
#define D_IN 14
#define H 128

typedef __attribute__((ext_vector_type(8))) short bf16x8;
typedef __attribute__((ext_vector_type(4))) float f32x4;

__device__ __forceinline__ unsigned short f2bf(float f) {
  unsigned int u = __float_as_uint(f);
  u += 0x7fffu + ((u >> 16) & 1u);
  return (unsigned short)(u >> 16);
}
__device__ __forceinline__ float bflo(unsigned int u) { return __uint_as_float(u << 16); }
__device__ __forceinline__ float bfhi(unsigned int u) { return __uint_as_float(u & 0xffff0000u); }
__device__ __forceinline__ unsigned int packbf2(float a, float b) {
  return (unsigned int)f2bf(a) | ((unsigned int)f2bf(b) << 16);
}

// ---------------- CSR build ----------------
__global__ __launch_bounds__(256) void k_hist(const int* __restrict__ rows, const int* __restrict__ cols,
                                              int* __restrict__ rcnt, int* __restrict__ ccnt) {
  int i = blockIdx.x * 256 + threadIdx.x;
  if (i < NNZ) {
    atomicAdd(&rcnt[rows[i]], 1);
    atomicAdd(&ccnt[cols[i]], 1);
  }
}

__global__ __launch_bounds__(256) void k_scan_blk(const int* __restrict__ cnt, int n,
                                                  int* __restrict__ off, int* __restrict__ bsum) {
  __shared__ int s[256];
  int t = threadIdx.x;
  int base = blockIdx.x * 1024 + t * 4;
  int v0 = (base + 0 < n) ? cnt[base + 0] : 0;
  int v1 = (base + 1 < n) ? cnt[base + 1] : 0;
  int v2 = (base + 2 < n) ? cnt[base + 2] : 0;
  int v3 = (base + 3 < n) ? cnt[base + 3] : 0;
  int sum = v0 + v1 + v2 + v3;
  s[t] = sum;
  __syncthreads();
  for (int o = 1; o < 256; o <<= 1) {
    int x = (t >= o) ? s[t - o] : 0;
    __syncthreads();
    s[t] += x;
    __syncthreads();
  }
  int excl = s[t] - sum;
  if (base + 0 < n) off[base + 0] = excl;
  if (base + 1 < n) off[base + 1] = excl + v0;
  if (base + 2 < n) off[base + 2] = excl + v0 + v1;
  if (base + 3 < n) off[base + 3] = excl + v0 + v1 + v2;
  if (t == 255) bsum[blockIdx.x] = s[255];
}

__global__ __launch_bounds__(256) void k_scan_top(int* __restrict__ bsum, int nb) {
  __shared__ int s[256];
  int t = threadIdx.x;
  int v = (t < nb) ? bsum[t] : 0;
  s[t] = v;
  __syncthreads();
  for (int o = 1; o < 256; o <<= 1) {
    int x = (t >= o) ? s[t - o] : 0;
    __syncthreads();
    s[t] += x;
    __syncthreads();
  }
  if (t < nb) bsum[t] = s[t] - v;
}

__global__ __launch_bounds__(256) void k_scan_fix(int* __restrict__ off, const int* __restrict__ bsum,
                                                  int n, int* __restrict__ cur) {
  int t = threadIdx.x;
  int add = bsum[blockIdx.x];
  int base = blockIdx.x * 1024 + t * 4;
#pragma unroll
  for (int j = 0; j < 4; j++) {
    int idx = base + j;
    if (idx < n) { int v = off[idx] + add; off[idx] = v; cur[idx] = v; }
  }
  if (blockIdx.x == 0 && t == 0) off[n] = NNZ;
}

__global__ __launch_bounds__(256) void k_fill(const int* __restrict__ rows, const int* __restrict__ cols,
                                              int* __restrict__ rcur, int* __restrict__ ccur,
                                              int* __restrict__ ridx, int* __restrict__ cidx) {
  int i = blockIdx.x * 256 + threadIdx.x;
  if (i < NNZ) {
    int r = rows[i], c = cols[i];
    int p = atomicAdd(&rcur[r], 1);
    ridx[p] = c;   // vertex r's incident edges
    int q = atomicAdd(&ccur[c], 1);
    cidx[q] = r;   // edge c's incident vertices
  }
}

// ---------------- input projection: x0 = x_0 @ W0_in + b0_in  (bf16 out) ----------------
__global__ __launch_bounds__(256) void k_inproj(const float* __restrict__ X, const float* __restrict__ W,
                                                const float* __restrict__ b, unsigned short* __restrict__ out) {
  __shared__ float Ws[D_IN * H];
  __shared__ float Bs[H];
  int t = threadIdx.x;
  for (int i = t; i < D_IN * H; i += 256) Ws[i] = W[i];
  if (t < H) Bs[t] = b[t];
  __syncthreads();
  int row = blockIdx.x * 16 + (t >> 4);
  int cg = (t & 15) * 8;
  float acc[8];
#pragma unroll
  for (int j = 0; j < 8; j++) acc[j] = Bs[cg + j];
#pragma unroll
  for (int k = 0; k < D_IN; k++) {
    float xv = X[row * D_IN + k];
#pragma unroll
    for (int j = 0; j < 8; j++) acc[j] += xv * Ws[k * H + cg + j];
  }
  unsigned int pk0 = packbf2(acc[0], acc[1]);
  unsigned int pk1 = packbf2(acc[2], acc[3]);
  unsigned int pk2 = packbf2(acc[4], acc[5]);
  unsigned int pk3 = packbf2(acc[6], acc[7]);
  *(uint4*)(out + (size_t)row * H + cg) = make_uint4(pk0, pk1, pk2, pk3);
}

// ---------------- GEMM: C[M,128] = bf16(A[M,128]) @ bf16(W[128,128]) + bias ----------------
__global__ __launch_bounds__(256) void k_gemm(const unsigned short* __restrict__ A,
                                              const float* __restrict__ W, const float* __restrict__ bias,
                                              unsigned short* __restrict__ C, int M) {
  __shared__ __align__(16) unsigned short Wf[32 * 64 * 8];  // per-(kc,nt) MFMA B-fragments
  __shared__ __align__(16) unsigned short Ct[64 * 136];     // output staging (padded)
  int t = threadIdx.x, lane = t & 63, wv = t >> 6;
  // stage W into MFMA B-fragment order: Wf[(kc*8+nt)*64+lane][j] = W[kc*32+(lane>>4)*8+j][nt*16+(lane&15)]
  for (int c = wv; c < 32; c += 4) {
    int kc = c >> 3, nt = c & 7;
    int n = nt * 16 + (lane & 15);
    int kb = kc * 32 + ((lane >> 4) << 3);
    __align__(16) unsigned short vals[8];
#pragma unroll
    for (int j = 0; j < 8; j++) vals[j] = f2bf(W[(kb + j) * H + n]);
    *(uint4*)(&Wf[(c * 64 + lane) * 8]) = *(uint4*)vals;
  }
  __syncthreads();
  long row = (long)blockIdx.x * 64 + wv * 16 + (lane & 15);
  int koff = (lane >> 4) << 3;
  f32x4 acc[8];
#pragma unroll
  for (int nt = 0; nt < 8; nt++) acc[nt] = (f32x4){0.f, 0.f, 0.f, 0.f};
#pragma unroll
  for (int kc = 0; kc < 4; kc++) {
    bf16x8 af = *(const bf16x8*)(A + row * H + kc * 32 + koff);
#pragma unroll
    for (int nt = 0; nt < 8; nt++) {
      bf16x8 bf = *(const bf16x8*)(&Wf[((kc * 8 + nt) * 64 + lane) * 8]);
      acc[nt] = __builtin_amdgcn_mfma_f32_16x16x32_bf16(af, bf, acc[nt], 0, 0, 0);
    }
  }
  // C/D layout: col = lane&15, row = (lane>>4)*4 + reg
  int crow = wv * 16 + ((lane >> 4) << 2);
#pragma unroll
  for (int nt = 0; nt < 8; nt++) {
    int col = nt * 16 + (lane & 15);
    float bv = bias[col];
#pragma unroll
    for (int r = 0; r < 4; r++) Ct[(crow + r) * 136 + col] = f2bf(acc[nt][r] + bv);
  }
  __syncthreads();
  long orow = (long)blockIdx.x * 64 + (t >> 2);
  if (orow < M) {
    int cb = (t & 3) * 32;
    const unsigned short* src = &Ct[(t >> 2) * 136 + cb];
    unsigned short* dst = C + orow * H + cb;
#pragma unroll
    for (int j = 0; j < 4; j++) *(uint4*)(dst + j * 8) = *(const uint4*)(src + j * 8);
  }
}

// ---------------- e = segment_sum(h[rows], cols)  (one wave per edge) ----------------
__global__ __launch_bounds__(256) void k_epass(const unsigned short* __restrict__ h,
                                               const int* __restrict__ coff, const int* __restrict__ cidx,
                                               unsigned short* __restrict__ e, float* __restrict__ colsum) {
  __shared__ float cacc[128];
  int t = threadIdx.x, lane = t & 63;
  if (colsum) {
    if (t < 128) cacc[t] = 0.f;
    __syncthreads();
  }
  int gw = blockIdx.x * 4 + (t >> 6);
  int nw = gridDim.x * 4;
  float cs0 = 0.f, cs1 = 0.f;
  for (int j = gw; j < N_E; j += nw) {
    int o0 = coff[j], n = coff[j + 1] - o0;
    float a0 = 0.f, a1 = 0.f;
    for (int s = 0; s < n; ++s) {
      int v = cidx[o0 + s];
      unsigned int u = *(const unsigned int*)(h + (size_t)v * H + (lane << 1));
      a0 += bflo(u); a1 += bfhi(u);
    }
    *(unsigned int*)(e + (size_t)j * H + (lane << 1)) = packbf2(a0, a1);
    cs0 += a0; cs1 += a1;
  }
  if (colsum) {
    atomicAdd(&cacc[lane << 1], cs0);
    atomicAdd(&cacc[(lane << 1) + 1], cs1);
    __syncthreads();
    if (t < 128) atomicAdd(&colsum[t], cacc[t]);
  }
}

// ---------------- m-pass: a2 = h + segsum(e[cols],rows)/deg  OR  colsum += h + m ----------------
__global__ __launch_bounds__(256) void k_mpass(const unsigned short* __restrict__ e,
                                               const int* __restrict__ roff, const int* __restrict__ ridx,
                                               const unsigned short* __restrict__ h,
                                               unsigned short* __restrict__ a2out,
                                               float* __restrict__ colsum) {
  __shared__ float cacc[128];
  int t = threadIdx.x, lane = t & 63;
  if (colsum) {
    if (t < 128) cacc[t] = 0.f;
    __syncthreads();
  }
  int gw = blockIdx.x * 4 + (t >> 6);
  int nw = gridDim.x * 4;
  float cs0 = 0.f, cs1 = 0.f;
  for (int v = gw; v < N_V; v += nw) {
    int o0 = roff[v], n = roff[v + 1] - o0;
    float a0 = 0.f, a1 = 0.f;
    for (int s = 0; s < n; ++s) {
      int j = ridx[o0 + s];
      unsigned int u = *(const unsigned int*)(e + (size_t)j * H + (lane << 1));
      a0 += bflo(u); a1 += bfhi(u);
    }
    float inv = (n > 0) ? (1.f / (float)n) : 1.f;
    unsigned int uh = *(const unsigned int*)(h + (size_t)v * H + (lane << 1));
    float r0 = bflo(uh) + a0 * inv;
    float r1 = bfhi(uh) + a1 * inv;
    if (a2out) {
      *(unsigned int*)(a2out + (size_t)v * H + (lane << 1)) = packbf2(r0, r1);
    } else {
      cs0 += r0; cs1 += r1;
    }
  }
  if (colsum) {
    atomicAdd(&cacc[lane << 1], cs0);
    atomicAdd(&cacc[(lane << 1) + 1], cs1);
    __syncthreads();
    if (t < 128) atomicAdd(&colsum[t], cacc[t]);
  }
}

// ---------------- final scalar ----------------
__global__ __launch_bounds__(128) void k_final(const float* __restrict__ csx, const float* __restrict__ cse,
                                               const float* __restrict__ Wo0, const float* __restrict__ bo0,
                                               const float* __restrict__ Wo1, const float* __restrict__ bo1,
                                               float* __restrict__ out) {
  __shared__ float red[128];
  int t = threadIdx.x;
  float v = csx[t] * (1.0f / (float)N_V) * Wo0[t] + cse[t] * (1.0f / (float)N_E) * Wo1[t];
  red[t] = v;
  __syncthreads();
  for (int o = 64; o > 0; o >>= 1) {
    if (t < o) red[t] += red[t + o];
    __syncthreads();
  }
  if (t == 0) out[0] = red[0] + bo0[0] + bo1[0];
}

extern "C" void kernel_launch(void* const* d_in, const int* in_sizes, int n_in,
                              void* d_out, int out_size, void* d_ws, size_t ws_size,
                              hipStream_t stream) {
  const float* x0in = (const float*)d_in[0];
  const int* rows   = (const int*)d_in[2];
  const int* cols   = (const int*)d_in[3];
  const float* W0   = (const float*)d_in[4];
  const float* b0   = (const float*)d_in[5];
  const float* Wl0  = (const float*)d_in[8];
  const float* bl0  = (const float*)d_in[9];
  const float* Wl1  = (const float*)d_in[10];
  const float* bl1  = (const float*)d_in[11];
  const float* Wo0  = (const float*)d_in[12];
  const float* bo0  = (const float*)d_in[13];
  const float* Wo1  = (const float*)d_in[14];
  const float* bo1  = (const float*)d_in[15];
  float* out = (float*)d_out;
  char* ws = (char*)d_ws;

  // workspace layout (zero region first, one memset covers it)
  int*   rcnt = (int*)(ws + 0);              //   400000 B
  int*   ccnt = (int*)(ws + 400000);         //   800000 B
  float* csx  = (float*)(ws + 1200000);      //      512 B
  float* cse  = (float*)(ws + 1200512);      //      512 B  -> zero 1201024 B
  int*   roff = (int*)(ws + 1201152);        //   400004 B
  int*   coff = (int*)(ws + 1601280);        //   800004 B
  int*   rcur = (int*)(ws + 2401408);        //   400000 B
  int*   ccur = (int*)(ws + 2801408);        //   800000 B
  int*   ridx = (int*)(ws + 3601408);        //  3200000 B
  int*   cidx = (int*)(ws + 6801408);        //  3200000 B
  int*   bsR  = (int*)(ws + 10001408);       //     1024 B
  int*   bsC  = (int*)(ws + 10002432);       //     1024 B
  unsigned short* xb = (unsigned short*)(ws + 10003456);  // 100032*128 bf16 = 25608192 B (x0, then a2)
  unsigned short* hb = (unsigned short*)(ws + 35611648);  // 25608192 B (h1, then h2)
  unsigned short* eb = (unsigned short*)(ws + 61219840);  // 200000*128 bf16 = 51200000 B (e1, then e2)
  // total: 112419840 B

  hipMemsetAsync(ws, 0, 1201024, stream);
  k_hist<<<dim3((NNZ + 255) / 256), dim3(256), 0, stream>>>(rows, cols, rcnt, ccnt);
  k_scan_blk<<<dim3(98),  dim3(256), 0, stream>>>(rcnt, N_V, roff, bsR);
  k_scan_blk<<<dim3(196), dim3(256), 0, stream>>>(ccnt, N_E, coff, bsC);
  k_scan_top<<<dim3(1), dim3(256), 0, stream>>>(bsR, 98);
  k_scan_top<<<dim3(1), dim3(256), 0, stream>>>(bsC, 196);
  k_scan_fix<<<dim3(98),  dim3(256), 0, stream>>>(roff, bsR, N_V, rcur);
  k_scan_fix<<<dim3(196), dim3(256), 0, stream>>>(coff, bsC, N_E, ccur);
  k_fill<<<dim3((NNZ + 255) / 256), dim3(256), 0, stream>>>(rows, cols, rcur, ccur, ridx, cidx);

  k_inproj<<<dim3(N_V / 16), dim3(256), 0, stream>>>(x0in, W0, b0, xb);
  k_gemm<<<dim3((N_V + 63) / 64), dim3(256), 0, stream>>>(xb, Wl0, bl0, hb, N_V);          // h1
  k_epass<<<dim3(2048), dim3(256), 0, stream>>>(hb, coff, cidx, eb, nullptr);              // e1
  k_mpass<<<dim3(2048), dim3(256), 0, stream>>>(eb, roff, ridx, hb, xb, nullptr);          // a2 = h1+m1
  k_gemm<<<dim3((N_V + 63) / 64), dim3(256), 0, stream>>>(xb, Wl1, bl1, hb, N_V);          // h2
  k_epass<<<dim3(2048), dim3(256), 0, stream>>>(hb, coff, cidx, eb, cse);                  // e2 + colsum(e2)
  k_mpass<<<dim3(2048), dim3(256), 0, stream>>>(eb, roff, ridx, hb, nullptr, csx);         // colsum(h2+m2)
  k_final<<<dim3(1), dim3(128), 0, stream>>>(csx, cse, Wo0, bo0, Wo1, bo1, out);
}

// Round 2
// 561.224 us; speedup vs baseline: 1.3427x; 1.3427x over previous
//
#include <hip/hip_runtime.h>
#include <stdint.h>

#define N_V 100000
#define N_E 200000
#define NNZ 800000
#define D_IN 14
#define H 128

typedef __attribute__((ext_vector_type(8))) short bf16x8;
typedef __attribute__((ext_vector_type(4))) float f32x4;

__device__ __forceinline__ unsigned short f2bf(float f) {
  unsigned int u = __float_as_uint(f);
  u += 0x7fffu + ((u >> 16) & 1u);
  return (unsigned short)(u >> 16);
}
__device__ __forceinline__ float bflo(unsigned int u) { return __uint_as_float(u << 16); }
__device__ __forceinline__ float bfhi(unsigned int u) { return __uint_as_float(u & 0xffff0000u); }
__device__ __forceinline__ unsigned int packbf2(float a, float b) {
  return (unsigned int)f2bf(a) | ((unsigned int)f2bf(b) << 16);
}

// ---------------- CSR build: histogram ----------------
__global__ __launch_bounds__(256) void k_hist(const int* __restrict__ rows, const int* __restrict__ cols,
                                              int* __restrict__ rcnt, int* __restrict__ ccnt) {
  int i = blockIdx.x * 256 + threadIdx.x;
  if (i < NNZ) {
    atomicAdd(&rcnt[rows[i]], 1);
    atomicAdd(&ccnt[cols[i]], 1);
  }
}

__global__ __launch_bounds__(256) void k_scan_blk(const int* __restrict__ cnt, int n,
                                                  int* __restrict__ off, int* __restrict__ bsum) {
  __shared__ int s[256];
  int t = threadIdx.x;
  int base = blockIdx.x * 1024 + t * 4;
  int v0 = (base + 0 < n) ? cnt[base + 0] : 0;
  int v1 = (base + 1 < n) ? cnt[base + 1] : 0;
  int v2 = (base + 2 < n) ? cnt[base + 2] : 0;
  int v3 = (base + 3 < n) ? cnt[base + 3] : 0;
  int sum = v0 + v1 + v2 + v3;
  s[t] = sum;
  __syncthreads();
  for (int o = 1; o < 256; o <<= 1) {
    int x = (t >= o) ? s[t - o] : 0;
    __syncthreads();
    s[t] += x;
    __syncthreads();
  }
  int excl = s[t] - sum;
  if (base + 0 < n) off[base + 0] = excl;
  if (base + 1 < n) off[base + 1] = excl + v0;
  if (base + 2 < n) off[base + 2] = excl + v0 + v1;
  if (base + 3 < n) off[base + 3] = excl + v0 + v1 + v2;
  if (t == 255) bsum[blockIdx.x] = s[255];
}

__global__ __launch_bounds__(256) void k_scan_top(int* __restrict__ bsum, int nb) {
  __shared__ int s[256];
  int t = threadIdx.x;
  int v = (t < nb) ? bsum[t] : 0;
  s[t] = v;
  __syncthreads();
  for (int o = 1; o < 256; o <<= 1) {
    int x = (t >= o) ? s[t - o] : 0;
    __syncthreads();
    s[t] += x;
    __syncthreads();
  }
  if (t < nb) bsum[t] = s[t] - v;
}

__global__ __launch_bounds__(256) void k_scan_fix(int* __restrict__ off, const int* __restrict__ bsum,
                                                  int n, int* __restrict__ cur) {
  int t = threadIdx.x;
  int add = bsum[blockIdx.x];
  int base = blockIdx.x * 1024 + t * 4;
#pragma unroll
  for (int j = 0; j < 4; j++) {
    int idx = base + j;
    if (idx < n) { int v = off[idx] + add; off[idx] = v; cur[idx] = v; }
  }
  if (blockIdx.x == 0 && t == 0) off[n] = NNZ;
}

// init per-bucket global reservation cursors from CSR offsets
__global__ __launch_bounds__(256) void k_binit(const int* __restrict__ roff, const int* __restrict__ coff,
                                               int* __restrict__ gcurR, int* __restrict__ gcurC) {
  int t = threadIdx.x;
  if (t < 196) {
    gcurR[t] = roff[t << 9];
    gcurC[t] = coff[t << 10];
  }
}

// ---------------- binning pass: group (key,val) records by destination bucket, coalesced writes ----------------
__global__ __launch_bounds__(256) void k_bin(const int* __restrict__ keys, const int* __restrict__ vals,
                                             int shift, int nb, int* __restrict__ gcur,
                                             uint2* __restrict__ binned) {
  __shared__ int bcnt[256], bsc[256], bex[256], gb[256];
  __shared__ uint2 recs[4096];
  __shared__ unsigned char bid[4096];
  int t = threadIdx.x;
  bcnt[t] = 0;
  __syncthreads();
  int base = blockIdx.x * 4096;
  int k_[16], v_[16], lp[16];
  short bb[16];
#pragma unroll
  for (int u = 0; u < 16; u++) {
    int i = base + u * 256 + t;
    if (i < NNZ) {
      k_[u] = keys[i]; v_[u] = vals[i];
      int b = k_[u] >> shift;
      bb[u] = (short)b;
      lp[u] = atomicAdd(&bcnt[b], 1);
    } else bb[u] = -1;
  }
  __syncthreads();
  bsc[t] = bcnt[t];
  __syncthreads();
  for (int o = 1; o < 256; o <<= 1) {
    int x = (t >= o) ? bsc[t - o] : 0;
    __syncthreads();
    bsc[t] += x;
    __syncthreads();
  }
  bex[t] = bsc[t] - bcnt[t];
  __syncthreads();
#pragma unroll
  for (int u = 0; u < 16; u++) {
    if (bb[u] >= 0) {
      int p = bex[bb[u]] + lp[u];
      recs[p] = make_uint2((unsigned)k_[u], (unsigned)v_[u]);
      bid[p] = (unsigned char)bb[u];
    }
  }
  if (t < nb && bcnt[t] > 0) gb[t] = atomicAdd(&gcur[t], bcnt[t]);
  __syncthreads();
  int total = bsc[255];
  for (int p = t; p < total; p += 256) {
    int b = bid[p];
    binned[gb[b] + (p - bex[b])] = recs[p];
  }
}

// ---------------- fine pass: per-bucket CSR scatter in LDS, coalesced write-out ----------------
__global__ __launch_bounds__(256) void k_fine(const uint2* __restrict__ binned, const int* __restrict__ off,
                                              int* __restrict__ idx, int* __restrict__ gcurFB,
                                              int shift, int n_keys) {
  __shared__ int cur[1024];
  __shared__ int vals[6144];
  int t = threadIdx.x;
  int kbase = blockIdx.x << shift;
  int kend = kbase + (1 << shift);
  if (kend > n_keys) kend = n_keys;
  int lo = off[kbase], hi = off[kend];
  int cnt = hi - lo;
  for (int r = t; r < kend - kbase; r += 256) cur[r] = off[kbase + r] - lo;
  __syncthreads();
  if (cnt <= 6144) {
    for (int p = t; p < cnt; p += 256) {
      uint2 rec = binned[lo + p];
      int pos = atomicAdd(&cur[(int)rec.x - kbase], 1);
      vals[pos] = (int)rec.y;
    }
    __syncthreads();
    for (int p = t; p < cnt; p += 256) idx[lo + p] = vals[p];
  } else {
    for (int p = t; p < cnt; p += 256) {
      uint2 rec = binned[lo + p];
      int pos = atomicAdd(&gcurFB[rec.x], 1);
      idx[pos] = (int)rec.y;
    }
  }
}

// ---------------- input projection: x0 = x_0 @ W0_in + b0_in  (bf16 out) ----------------
__global__ __launch_bounds__(256) void k_inproj(const float* __restrict__ X, const float* __restrict__ W,
                                                const float* __restrict__ b, unsigned short* __restrict__ out) {
  __shared__ float Ws[D_IN * H];
  __shared__ float Bs[H];
  int t = threadIdx.x;
  for (int i = t; i < D_IN * H; i += 256) Ws[i] = W[i];
  if (t < H) Bs[t] = b[t];
  __syncthreads();
  int row = blockIdx.x * 16 + (t >> 4);
  int cg = (t & 15) * 8;
  float acc[8];
#pragma unroll
  for (int j = 0; j < 8; j++) acc[j] = Bs[cg + j];
#pragma unroll
  for (int k = 0; k < D_IN; k++) {
    float xv = X[row * D_IN + k];
#pragma unroll
    for (int j = 0; j < 8; j++) acc[j] += xv * Ws[k * H + cg + j];
  }
  unsigned int pk0 = packbf2(acc[0], acc[1]);
  unsigned int pk1 = packbf2(acc[2], acc[3]);
  unsigned int pk2 = packbf2(acc[4], acc[5]);
  unsigned int pk3 = packbf2(acc[6], acc[7]);
  *(uint4*)(out + (size_t)row * H + cg) = make_uint4(pk0, pk1, pk2, pk3);
}

// ---------------- GEMM: C[M,128] = bf16(A[M,128]) @ bf16(W[128,128]) + bias ----------------
__global__ __launch_bounds__(256) void k_gemm(const unsigned short* __restrict__ A,
                                              const float* __restrict__ W, const float* __restrict__ bias,
                                              unsigned short* __restrict__ C, int M) {
  __shared__ __align__(16) unsigned short Wf[32 * 64 * 8];
  __shared__ __align__(16) unsigned short Ct[64 * 136];
  int t = threadIdx.x, lane = t & 63, wv = t >> 6;
  for (int c = wv; c < 32; c += 4) {
    int kc = c >> 3, nt = c & 7;
    int n = nt * 16 + (lane & 15);
    int kb = kc * 32 + ((lane >> 4) << 3);
    __align__(16) unsigned short vals[8];
#pragma unroll
    for (int j = 0; j < 8; j++) vals[j] = f2bf(W[(kb + j) * H + n]);
    *(uint4*)(&Wf[(c * 64 + lane) * 8]) = *(uint4*)vals;
  }
  __syncthreads();
  long row = (long)blockIdx.x * 64 + wv * 16 + (lane & 15);
  int koff = (lane >> 4) << 3;
  f32x4 acc[8];
#pragma unroll
  for (int nt = 0; nt < 8; nt++) acc[nt] = (f32x4){0.f, 0.f, 0.f, 0.f};
#pragma unroll
  for (int kc = 0; kc < 4; kc++) {
    bf16x8 af = *(const bf16x8*)(A + row * H + kc * 32 + koff);
#pragma unroll
    for (int nt = 0; nt < 8; nt++) {
      bf16x8 bf = *(const bf16x8*)(&Wf[((kc * 8 + nt) * 64 + lane) * 8]);
      acc[nt] = __builtin_amdgcn_mfma_f32_16x16x32_bf16(af, bf, acc[nt], 0, 0, 0);
    }
  }
  int crow = wv * 16 + ((lane >> 4) << 2);
#pragma unroll
  for (int nt = 0; nt < 8; nt++) {
    int col = nt * 16 + (lane & 15);
    float bv = bias[col];
#pragma unroll
    for (int r = 0; r < 4; r++) Ct[(crow + r) * 136 + col] = f2bf(acc[nt][r] + bv);
  }
  __syncthreads();
  long orow = (long)blockIdx.x * 64 + (t >> 2);
  if (orow < M) {
    int cb = (t & 3) * 32;
    const unsigned short* src = &Ct[(t >> 2) * 136 + cb];
    unsigned short* dst = C + orow * H + cb;
#pragma unroll
    for (int j = 0; j < 4; j++) *(uint4*)(dst + j * 8) = *(const uint4*)(src + j * 8);
  }
}

// ---------------- e = segment_sum(h[rows], cols)  (one wave per edge, 4 gathers in flight) ----------------
__global__ __launch_bounds__(256) void k_epass(const unsigned short* __restrict__ h,
                                               const int* __restrict__ coff, const int* __restrict__ cidx,
                                               unsigned short* __restrict__ e, float* __restrict__ colsum) {
  __shared__ float cacc[128];
  int t = threadIdx.x, lane = t & 63, la = lane << 1;
  if (colsum) {
    if (t < 128) cacc[t] = 0.f;
    __syncthreads();
  }
  int gw = blockIdx.x * 4 + (t >> 6);
  int nw = gridDim.x * 4;
  float cs0 = 0.f, cs1 = 0.f;
  for (int j = gw; j < N_E; j += nw) {
    int o0 = coff[j], n = coff[j + 1] - o0;
    float a0 = 0.f, a1 = 0.f;
    int s = 0;
    for (; s + 4 <= n; s += 4) {
      int v0 = cidx[o0 + s], v1 = cidx[o0 + s + 1], v2 = cidx[o0 + s + 2], v3 = cidx[o0 + s + 3];
      unsigned u0 = *(const unsigned*)(h + (size_t)v0 * H + la);
      unsigned u1 = *(const unsigned*)(h + (size_t)v1 * H + la);
      unsigned u2 = *(const unsigned*)(h + (size_t)v2 * H + la);
      unsigned u3 = *(const unsigned*)(h + (size_t)v3 * H + la);
      a0 += (bflo(u0) + bflo(u1)) + (bflo(u2) + bflo(u3));
      a1 += (bfhi(u0) + bfhi(u1)) + (bfhi(u2) + bfhi(u3));
    }
    for (; s < n; ++s) {
      unsigned u = *(const unsigned*)(h + (size_t)cidx[o0 + s] * H + la);
      a0 += bflo(u); a1 += bfhi(u);
    }
    *(unsigned*)(e + (size_t)j * H + la) = packbf2(a0, a1);
    cs0 += a0; cs1 += a1;
  }
  if (colsum) {
    atomicAdd(&cacc[la], cs0);
    atomicAdd(&cacc[la + 1], cs1);
    __syncthreads();
    if (t < 128) atomicAdd(&colsum[t], cacc[t]);
  }
}

// ---------------- m-pass: a2 = h + segsum(e[cols],rows)/deg  OR  colsum(h + m) ----------------
__global__ __launch_bounds__(256) void k_mpass(const unsigned short* __restrict__ e,
                                               const int* __restrict__ roff, const int* __restrict__ ridx,
                                               const unsigned short* __restrict__ h,
                                               unsigned short* __restrict__ a2out,
                                               float* __restrict__ colsum) {
  __shared__ float cacc[128];
  int t = threadIdx.x, lane = t & 63, la = lane << 1;
  if (colsum) {
    if (t < 128) cacc[t] = 0.f;
    __syncthreads();
  }
  int gw = blockIdx.x * 4 + (t >> 6);
  int nw = gridDim.x * 4;
  float cs0 = 0.f, cs1 = 0.f;
  for (int v = gw; v < N_V; v += nw) {
    int o0 = roff[v], n = roff[v + 1] - o0;
    float a0 = 0.f, a1 = 0.f;
    int s = 0;
    for (; s + 4 <= n; s += 4) {
      int j0 = ridx[o0 + s], j1 = ridx[o0 + s + 1], j2 = ridx[o0 + s + 2], j3 = ridx[o0 + s + 3];
      unsigned u0 = *(const unsigned*)(e + (size_t)j0 * H + la);
      unsigned u1 = *(const unsigned*)(e + (size_t)j1 * H + la);
      unsigned u2 = *(const unsigned*)(e + (size_t)j2 * H + la);
      unsigned u3 = *(const unsigned*)(e + (size_t)j3 * H + la);
      a0 += (bflo(u0) + bflo(u1)) + (bflo(u2) + bflo(u3));
      a1 += (bfhi(u0) + bfhi(u1)) + (bfhi(u2) + bfhi(u3));
    }
    for (; s < n; ++s) {
      unsigned u = *(const unsigned*)(e + (size_t)ridx[o0 + s] * H + la);
      a0 += bflo(u); a1 += bfhi(u);
    }
    float inv = (n > 0) ? (1.f / (float)n) : 1.f;
    unsigned uh = *(const unsigned*)(h + (size_t)v * H + la);
    float r0 = bflo(uh) + a0 * inv;
    float r1 = bfhi(uh) + a1 * inv;
    if (a2out) {
      *(unsigned*)(a2out + (size_t)v * H + la) = packbf2(r0, r1);
    } else {
      cs0 += r0; cs1 += r1;
    }
  }
  if (colsum) {
    atomicAdd(&cacc[la], cs0);
    atomicAdd(&cacc[la + 1], cs1);
    __syncthreads();
    if (t < 128) atomicAdd(&colsum[t], cacc[t]);
  }
}

// ---------------- Q = sum_v (1/deg_v) * sum_{j in edges(v)} ccnt[j] ----------------
__global__ __launch_bounds__(256) void k_qsum(const int* __restrict__ roff, const int* __restrict__ ridx,
                                              const int* __restrict__ ccnt, float* __restrict__ qsum) {
  __shared__ float red[256];
  int t = threadIdx.x;
  int v = blockIdx.x * 256 + t;
  float q = 0.f;
  if (v < N_V) {
    int o0 = roff[v], n = roff[v + 1] - o0;
    float s = 0.f;
    for (int k = 0; k < n; k++) s += (float)ccnt[ridx[o0 + k]];
    q = (n > 0) ? s / (float)n : 0.f;
  }
  red[t] = q;
  __syncthreads();
  for (int o = 128; o > 0; o >>= 1) {
    if (t < o) red[t] += red[t + o];
    __syncthreads();
  }
  if (t == 0) atomicAdd(qsum, red[0]);
}

// ---------------- final: push Wl1 through the colsums, then output heads ----------------
__global__ __launch_bounds__(128) void k_final(const float* __restrict__ cAM, const float* __restrict__ cE,
                                               const float* __restrict__ qsum,
                                               const float* __restrict__ Wl1, const float* __restrict__ bl1,
                                               const float* __restrict__ Wo0, const float* __restrict__ bo0,
                                               const float* __restrict__ Wo1, const float* __restrict__ bo1,
                                               float* __restrict__ out) {
  __shared__ float red[128];
  int t = threadIdx.x;
  float sx = 0.f, se = 0.f;
  for (int k = 0; k < H; k++) {
    float w = Wl1[k * H + t];
    sx += cAM[k] * w;
    se += cE[k] * w;
  }
  float Q = qsum[0];
  sx += ((float)N_V + Q) * bl1[t];
  se += (float)NNZ * bl1[t];
  float v = sx * (1.0f / (float)N_V) * Wo0[t] + se * (1.0f / (float)N_E) * Wo1[t];
  red[t] = v;
  __syncthreads();
  for (int o = 64; o > 0; o >>= 1) {
    if (t < o) red[t] += red[t + o];
    __syncthreads();
  }
  if (t == 0) out[0] = red[0] + bo0[0] + bo1[0];
}

extern "C" void kernel_launch(void* const* d_in, const int* in_sizes, int n_in,
                              void* d_out, int out_size, void* d_ws, size_t ws_size,
                              hipStream_t stream) {
  const float* x0in = (const float*)d_in[0];
  const int* rows   = (const int*)d_in[2];
  const int* cols   = (const int*)d_in[3];
  const float* W0   = (const float*)d_in[4];
  const float* b0   = (const float*)d_in[5];
  const float* Wl0  = (const float*)d_in[8];
  const float* bl0  = (const float*)d_in[9];
  const float* Wl1  = (const float*)d_in[10];
  const float* bl1  = (const float*)d_in[11];
  const float* Wo0  = (const float*)d_in[12];
  const float* bo0  = (const float*)d_in[13];
  const float* Wo1  = (const float*)d_in[14];
  const float* bo1  = (const float*)d_in[15];
  float* out = (float*)d_out;
  char* ws = (char*)d_ws;

  // workspace layout
  int*   rcnt = (int*)(ws + 0);              //   400000
  int*   ccnt = (int*)(ws + 400000);         //   800000
  float* csx  = (float*)(ws + 1200000);      //      512
  float* cse  = (float*)(ws + 1200512);      //      512
  float* qsum = (float*)(ws + 1201024);      //        4   -> zero [0, 1201028)
  int*   roff = (int*)(ws + 1201152);        //   400004
  int*   coff = (int*)(ws + 1601280);        //   800004
  int*   rcur = (int*)(ws + 2401408);        //   400000
  int*   ccur = (int*)(ws + 2801408);        //   800000
  int*   ridx = (int*)(ws + 3601408);        //  3200000
  int*   cidx = (int*)(ws + 6801408);        //  3200000
  int*   bsR  = (int*)(ws + 10001408);       //     1024
  int*   bsC  = (int*)(ws + 10002432);       //     1024
  int*   gcurR= (int*)(ws + 10003456);       //     1024
  int*   gcurC= (int*)(ws + 10004480);       //     1024
  unsigned short* xb = (unsigned short*)(ws + 10005504);  // 100032*128 bf16 = 25608192 (x0, then a2)
  unsigned short* hb = (unsigned short*)(ws + 35613696);  // 25608192 (h1)
  unsigned short* eb = (unsigned short*)(ws + 61221888);  // 200000*128 bf16 = 51200000 (e1, then Ea)
  // binned record temps alias the hb region (hb written only after fine passes complete)
  uint2* binnedR = (uint2*)(ws + 35613696);               // 6400000
  uint2* binnedC = (uint2*)(ws + 42013696);               // 6400000
  // total: 112421888 B

  hipMemsetAsync(ws, 0, 1201028, stream);
  k_hist<<<dim3((NNZ + 255) / 256), dim3(256), 0, stream>>>(rows, cols, rcnt, ccnt);
  k_scan_blk<<<dim3(98),  dim3(256), 0, stream>>>(rcnt, N_V, roff, bsR);
  k_scan_blk<<<dim3(196), dim3(256), 0, stream>>>(ccnt, N_E, coff, bsC);
  k_scan_top<<<dim3(1), dim3(256), 0, stream>>>(bsR, 98);
  k_scan_top<<<dim3(1), dim3(256), 0, stream>>>(bsC, 196);
  k_scan_fix<<<dim3(98),  dim3(256), 0, stream>>>(roff, bsR, N_V, rcur);
  k_scan_fix<<<dim3(196), dim3(256), 0, stream>>>(coff, bsC, N_E, ccur);
  k_binit<<<dim3(1), dim3(256), 0, stream>>>(roff, coff, gcurR, gcurC);
  k_bin<<<dim3(196), dim3(256), 0, stream>>>(rows, cols, 9, 196, gcurR, binnedR);
  k_bin<<<dim3(196), dim3(256), 0, stream>>>(cols, rows, 10, 196, gcurC, binnedC);
  k_fine<<<dim3(196), dim3(256), 0, stream>>>(binnedR, roff, ridx, rcur, 9, N_V);
  k_fine<<<dim3(196), dim3(256), 0, stream>>>(binnedC, coff, cidx, ccur, 10, N_E);

  k_inproj<<<dim3(N_V / 16), dim3(256), 0, stream>>>(x0in, W0, b0, xb);
  k_gemm<<<dim3((N_V + 63) / 64), dim3(256), 0, stream>>>(xb, Wl0, bl0, hb, N_V);   // h1
  k_epass<<<dim3(2048), dim3(256), 0, stream>>>(hb, coff, cidx, eb, nullptr);       // e1
  k_mpass<<<dim3(2048), dim3(256), 0, stream>>>(eb, roff, ridx, hb, xb, nullptr);   // a2 = h1 + m1 (into xb)
  k_epass<<<dim3(2048), dim3(256), 0, stream>>>(xb, coff, cidx, eb, cse);           // Ea = B^T a2, cE
  k_qsum<<<dim3((N_V + 255) / 256), dim3(256), 0, stream>>>(roff, ridx, ccnt, qsum);
  k_mpass<<<dim3(2048), dim3(256), 0, stream>>>(eb, roff, ridx, xb, nullptr, csx);  // colsum(a2 + Ma)
  k_final<<<dim3(1), dim3(128), 0, stream>>>(csx, cse, qsum, Wl1, bl1, Wo0, bo0, Wo1, bo1, out);
}

// Round 3
// 539.372 us; speedup vs baseline: 1.3971x; 1.0405x over previous
//
#include <hip/hip_runtime.h>
#include <stdint.h>

#define N_V 100000
#define N_E 200000
#define NNZ 800000
#define D_IN 14
#define H 128

typedef __attribute__((ext_vector_type(8))) short bf16x8;
typedef __attribute__((ext_vector_type(4))) float f32x4;

__device__ __forceinline__ unsigned short f2bf(float f) {
  unsigned int u = __float_as_uint(f);
  u += 0x7fffu + ((u >> 16) & 1u);
  return (unsigned short)(u >> 16);
}
__device__ __forceinline__ float bflo(unsigned int u) { return __uint_as_float(u << 16); }
__device__ __forceinline__ float bfhi(unsigned int u) { return __uint_as_float(u & 0xffff0000u); }
__device__ __forceinline__ unsigned int packbf2(float a, float b) {
  return (unsigned int)f2bf(a) | ((unsigned int)f2bf(b) << 16);
}

// ---------------- CSR build: histogram ----------------
__global__ __launch_bounds__(256) void k_hist(const int* __restrict__ rows, const int* __restrict__ cols,
                                              int* __restrict__ rcnt, int* __restrict__ ccnt) {
  int i = blockIdx.x * 256 + threadIdx.x;
  if (i < NNZ) {
    atomicAdd(&rcnt[rows[i]], 1);
    atomicAdd(&ccnt[cols[i]], 1);
  }
}

__global__ __launch_bounds__(256) void k_scan_blk(const int* __restrict__ cnt, int n,
                                                  int* __restrict__ off, int* __restrict__ bsum) {
  __shared__ int s[256];
  int t = threadIdx.x;
  int base = blockIdx.x * 1024 + t * 4;
  int v0 = (base + 0 < n) ? cnt[base + 0] : 0;
  int v1 = (base + 1 < n) ? cnt[base + 1] : 0;
  int v2 = (base + 2 < n) ? cnt[base + 2] : 0;
  int v3 = (base + 3 < n) ? cnt[base + 3] : 0;
  int sum = v0 + v1 + v2 + v3;
  s[t] = sum;
  __syncthreads();
  for (int o = 1; o < 256; o <<= 1) {
    int x = (t >= o) ? s[t - o] : 0;
    __syncthreads();
    s[t] += x;
    __syncthreads();
  }
  int excl = s[t] - sum;
  if (base + 0 < n) off[base + 0] = excl;
  if (base + 1 < n) off[base + 1] = excl + v0;
  if (base + 2 < n) off[base + 2] = excl + v0 + v1;
  if (base + 3 < n) off[base + 3] = excl + v0 + v1 + v2;
  if (t == 255) bsum[blockIdx.x] = s[255];
}

__global__ __launch_bounds__(256) void k_scan_top(int* __restrict__ bsum, int nb) {
  __shared__ int s[256];
  int t = threadIdx.x;
  int v = (t < nb) ? bsum[t] : 0;
  s[t] = v;
  __syncthreads();
  for (int o = 1; o < 256; o <<= 1) {
    int x = (t >= o) ? s[t - o] : 0;
    __syncthreads();
    s[t] += x;
    __syncthreads();
  }
  if (t < nb) bsum[t] = s[t] - v;
}

__global__ __launch_bounds__(256) void k_scan_fix(int* __restrict__ off, const int* __restrict__ bsum,
                                                  int n, int* __restrict__ cur) {
  int t = threadIdx.x;
  int add = bsum[blockIdx.x];
  int base = blockIdx.x * 1024 + t * 4;
#pragma unroll
  for (int j = 0; j < 4; j++) {
    int idx = base + j;
    if (idx < n) { int v = off[idx] + add; off[idx] = v; cur[idx] = v; }
  }
  if (blockIdx.x == 0 && t == 0) off[n] = NNZ;
}

// init per-bucket global reservation cursors from CSR offsets
__global__ __launch_bounds__(256) void k_binit(const int* __restrict__ roff, const int* __restrict__ coff,
                                               int* __restrict__ gcurR, int* __restrict__ gcurC) {
  int t = threadIdx.x;
  if (t < 196) {
    gcurR[t] = roff[t << 9];
    gcurC[t] = coff[t << 10];
  }
}

// ---------------- binning pass ----------------
__global__ __launch_bounds__(256) void k_bin(const int* __restrict__ keys, const int* __restrict__ vals,
                                             int shift, int nb, int* __restrict__ gcur,
                                             uint2* __restrict__ binned) {
  __shared__ int bcnt[256], bsc[256], bex[256], gb[256];
  __shared__ uint2 recs[4096];
  __shared__ unsigned char bid[4096];
  int t = threadIdx.x;
  bcnt[t] = 0;
  __syncthreads();
  int base = blockIdx.x * 4096;
  int k_[16], v_[16], lp[16];
  short bb[16];
#pragma unroll
  for (int u = 0; u < 16; u++) {
    int i = base + u * 256 + t;
    if (i < NNZ) {
      k_[u] = keys[i]; v_[u] = vals[i];
      int b = k_[u] >> shift;
      bb[u] = (short)b;
      lp[u] = atomicAdd(&bcnt[b], 1);
    } else bb[u] = -1;
  }
  __syncthreads();
  bsc[t] = bcnt[t];
  __syncthreads();
  for (int o = 1; o < 256; o <<= 1) {
    int x = (t >= o) ? bsc[t - o] : 0;
    __syncthreads();
    bsc[t] += x;
    __syncthreads();
  }
  bex[t] = bsc[t] - bcnt[t];
  __syncthreads();
#pragma unroll
  for (int u = 0; u < 16; u++) {
    if (bb[u] >= 0) {
      int p = bex[bb[u]] + lp[u];
      recs[p] = make_uint2((unsigned)k_[u], (unsigned)v_[u]);
      bid[p] = (unsigned char)bb[u];
    }
  }
  if (t < nb && bcnt[t] > 0) gb[t] = atomicAdd(&gcur[t], bcnt[t]);
  __syncthreads();
  int total = bsc[255];
  for (int p = t; p < total; p += 256) {
    int b = bid[p];
    binned[gb[b] + (p - bex[b])] = recs[p];
  }
}

// ---------------- fine pass ----------------
__global__ __launch_bounds__(256) void k_fine(const uint2* __restrict__ binned, const int* __restrict__ off,
                                              int* __restrict__ idx, int* __restrict__ gcurFB,
                                              int shift, int n_keys) {
  __shared__ int cur[1024];
  __shared__ int vals[6144];
  int t = threadIdx.x;
  int kbase = blockIdx.x << shift;
  int kend = kbase + (1 << shift);
  if (kend > n_keys) kend = n_keys;
  int lo = off[kbase], hi = off[kend];
  int cnt = hi - lo;
  for (int r = t; r < kend - kbase; r += 256) cur[r] = off[kbase + r] - lo;
  __syncthreads();
  if (cnt <= 6144) {
    for (int p = t; p < cnt; p += 256) {
      uint2 rec = binned[lo + p];
      int pos = atomicAdd(&cur[(int)rec.x - kbase], 1);
      vals[pos] = (int)rec.y;
    }
    __syncthreads();
    for (int p = t; p < cnt; p += 256) idx[lo + p] = vals[p];
  } else {
    for (int p = t; p < cnt; p += 256) {
      uint2 rec = binned[lo + p];
      int pos = atomicAdd(&gcurFB[rec.x], 1);
      idx[pos] = (int)rec.y;
    }
  }
}

// ---------------- input projection ----------------
__global__ __launch_bounds__(256) void k_inproj(const float* __restrict__ X, const float* __restrict__ W,
                                                const float* __restrict__ b, unsigned short* __restrict__ out) {
  __shared__ float Ws[D_IN * H];
  __shared__ float Bs[H];
  int t = threadIdx.x;
  for (int i = t; i < D_IN * H; i += 256) Ws[i] = W[i];
  if (t < H) Bs[t] = b[t];
  __syncthreads();
  int row = blockIdx.x * 16 + (t >> 4);
  int cg = (t & 15) * 8;
  float acc[8];
#pragma unroll
  for (int j = 0; j < 8; j++) acc[j] = Bs[cg + j];
#pragma unroll
  for (int k = 0; k < D_IN; k++) {
    float xv = X[row * D_IN + k];
#pragma unroll
    for (int j = 0; j < 8; j++) acc[j] += xv * Ws[k * H + cg + j];
  }
  unsigned int pk0 = packbf2(acc[0], acc[1]);
  unsigned int pk1 = packbf2(acc[2], acc[3]);
  unsigned int pk2 = packbf2(acc[4], acc[5]);
  unsigned int pk3 = packbf2(acc[6], acc[7]);
  *(uint4*)(out + (size_t)row * H + cg) = make_uint4(pk0, pk1, pk2, pk3);
}

// ---------------- GEMM ----------------
__global__ __launch_bounds__(256) void k_gemm(const unsigned short* __restrict__ A,
                                              const float* __restrict__ W, const float* __restrict__ bias,
                                              unsigned short* __restrict__ C, int M) {
  __shared__ __align__(16) unsigned short Wf[32 * 64 * 8];
  __shared__ __align__(16) unsigned short Ct[64 * 136];
  int t = threadIdx.x, lane = t & 63, wv = t >> 6;
  for (int c = wv; c < 32; c += 4) {
    int kc = c >> 3, nt = c & 7;
    int n = nt * 16 + (lane & 15);
    int kb = kc * 32 + ((lane >> 4) << 3);
    __align__(16) unsigned short vals[8];
#pragma unroll
    for (int j = 0; j < 8; j++) vals[j] = f2bf(W[(kb + j) * H + n]);
    *(uint4*)(&Wf[(c * 64 + lane) * 8]) = *(uint4*)vals;
  }
  __syncthreads();
  long row = (long)blockIdx.x * 64 + wv * 16 + (lane & 15);
  int koff = (lane >> 4) << 3;
  f32x4 acc[8];
#pragma unroll
  for (int nt = 0; nt < 8; nt++) acc[nt] = (f32x4){0.f, 0.f, 0.f, 0.f};
#pragma unroll
  for (int kc = 0; kc < 4; kc++) {
    bf16x8 af = *(const bf16x8*)(A + row * H + kc * 32 + koff);
#pragma unroll
    for (int nt = 0; nt < 8; nt++) {
      bf16x8 bf = *(const bf16x8*)(&Wf[((kc * 8 + nt) * 64 + lane) * 8]);
      acc[nt] = __builtin_amdgcn_mfma_f32_16x16x32_bf16(af, bf, acc[nt], 0, 0, 0);
    }
  }
  int crow = wv * 16 + ((lane >> 4) << 2);
#pragma unroll
  for (int nt = 0; nt < 8; nt++) {
    int col = nt * 16 + (lane & 15);
    float bv = bias[col];
#pragma unroll
    for (int r = 0; r < 4; r++) Ct[(crow + r) * 136 + col] = f2bf(acc[nt][r] + bv);
  }
  __syncthreads();
  long orow = (long)blockIdx.x * 64 + (t >> 2);
  if (orow < M) {
    int cb = (t & 3) * 32;
    const unsigned short* src = &Ct[(t >> 2) * 136 + cb];
    unsigned short* dst = C + orow * H + cb;
#pragma unroll
    for (int j = 0; j < 4; j++) *(uint4*)(dst + j * 8) = *(const uint4*)(src + j * 8);
  }
}

// helper: accumulate 8 bf16 (uint4) into 8 floats
#define ACC8(a, u) do { \
  a[0] += bflo((u).x); a[1] += bfhi((u).x); \
  a[2] += bflo((u).y); a[3] += bfhi((u).y); \
  a[4] += bflo((u).z); a[5] += bfhi((u).z); \
  a[6] += bflo((u).w); a[7] += bfhi((u).w); } while (0)

// ---------------- e-pass: 4 edges per wave, 16 lanes x uint4 per edge ----------------
__global__ __launch_bounds__(256) void k_epass(const unsigned short* __restrict__ h,
                                               const int* __restrict__ coff, const int* __restrict__ cidx,
                                               unsigned short* __restrict__ e, float* __restrict__ colsum) {
  __shared__ float cacc[128];
  int t = threadIdx.x, lane = t & 63;
  int eg = lane >> 4, sl = lane & 15;
  if (colsum) {
    if (t < 128) cacc[t] = 0.f;
    __syncthreads();
  }
  int gw = blockIdx.x * 4 + (t >> 6);
  int nw = gridDim.x * 4;
  float cs[8] = {0.f, 0.f, 0.f, 0.f, 0.f, 0.f, 0.f, 0.f};
  const int NB = (N_E + 3) >> 2;
  for (int b = gw; b < NB; b += nw) {
    int j = b * 4 + eg;
    bool jv = j < N_E;
    int o0 = 0, n = 0;
    if (jv) { o0 = coff[j]; n = coff[j + 1] - o0; }
    float a[8] = {0.f, 0.f, 0.f, 0.f, 0.f, 0.f, 0.f, 0.f};
    int s = 0;
    for (; s + 4 <= n; s += 4) {
      int v0 = cidx[o0 + s], v1 = cidx[o0 + s + 1], v2 = cidx[o0 + s + 2], v3 = cidx[o0 + s + 3];
      uint4 u0 = *(const uint4*)(h + (size_t)v0 * H + sl * 8);
      uint4 u1 = *(const uint4*)(h + (size_t)v1 * H + sl * 8);
      uint4 u2 = *(const uint4*)(h + (size_t)v2 * H + sl * 8);
      uint4 u3 = *(const uint4*)(h + (size_t)v3 * H + sl * 8);
      ACC8(a, u0); ACC8(a, u1); ACC8(a, u2); ACC8(a, u3);
    }
    for (; s < n; ++s) {
      int v = cidx[o0 + s];
      uint4 u = *(const uint4*)(h + (size_t)v * H + sl * 8);
      ACC8(a, u);
    }
    if (jv) {
      uint4 pk;
      pk.x = packbf2(a[0], a[1]); pk.y = packbf2(a[2], a[3]);
      pk.z = packbf2(a[4], a[5]); pk.w = packbf2(a[6], a[7]);
      *(uint4*)(e + (size_t)j * H + sl * 8) = pk;
      if (colsum) {
#pragma unroll
        for (int k = 0; k < 8; k++) cs[k] += a[k];
      }
    }
  }
  if (colsum) {
#pragma unroll
    for (int k = 0; k < 8; k++) {
      float v = cs[k];
      v += __shfl_xor(v, 16);
      v += __shfl_xor(v, 32);
      if (eg == 0) atomicAdd(&cacc[sl * 8 + k], v);
    }
    __syncthreads();
    if (t < 128) atomicAdd(&colsum[t], cacc[t]);
  }
}

// ---------------- m-pass: 4 vertices per wave ----------------
__global__ __launch_bounds__(256) void k_mpass(const unsigned short* __restrict__ e,
                                               const int* __restrict__ roff, const int* __restrict__ ridx,
                                               const unsigned short* __restrict__ h,
                                               unsigned short* __restrict__ a2out,
                                               float* __restrict__ colsum) {
  __shared__ float cacc[128];
  int t = threadIdx.x, lane = t & 63;
  int eg = lane >> 4, sl = lane & 15;
  if (colsum) {
    if (t < 128) cacc[t] = 0.f;
    __syncthreads();
  }
  int gw = blockIdx.x * 4 + (t >> 6);
  int nw = gridDim.x * 4;
  float cs[8] = {0.f, 0.f, 0.f, 0.f, 0.f, 0.f, 0.f, 0.f};
  const int NB = (N_V + 3) >> 2;
  for (int b = gw; b < NB; b += nw) {
    int v = b * 4 + eg;
    bool vv = v < N_V;
    int o0 = 0, n = 0;
    if (vv) { o0 = roff[v]; n = roff[v + 1] - o0; }
    float a[8] = {0.f, 0.f, 0.f, 0.f, 0.f, 0.f, 0.f, 0.f};
    int s = 0;
    for (; s + 4 <= n; s += 4) {
      int j0 = ridx[o0 + s], j1 = ridx[o0 + s + 1], j2 = ridx[o0 + s + 2], j3 = ridx[o0 + s + 3];
      uint4 u0 = *(const uint4*)(e + (size_t)j0 * H + sl * 8);
      uint4 u1 = *(const uint4*)(e + (size_t)j1 * H + sl * 8);
      uint4 u2 = *(const uint4*)(e + (size_t)j2 * H + sl * 8);
      uint4 u3 = *(const uint4*)(e + (size_t)j3 * H + sl * 8);
      ACC8(a, u0); ACC8(a, u1); ACC8(a, u2); ACC8(a, u3);
    }
    for (; s < n; ++s) {
      int j = ridx[o0 + s];
      uint4 u = *(const uint4*)(e + (size_t)j * H + sl * 8);
      ACC8(a, u);
    }
    if (vv) {
      float inv = (n > 0) ? (1.f / (float)n) : 1.f;
      uint4 uh = *(const uint4*)(h + (size_t)v * H + sl * 8);
      float r[8];
      r[0] = bflo(uh.x) + a[0] * inv; r[1] = bfhi(uh.x) + a[1] * inv;
      r[2] = bflo(uh.y) + a[2] * inv; r[3] = bfhi(uh.y) + a[3] * inv;
      r[4] = bflo(uh.z) + a[4] * inv; r[5] = bfhi(uh.z) + a[5] * inv;
      r[6] = bflo(uh.w) + a[6] * inv; r[7] = bfhi(uh.w) + a[7] * inv;
      if (a2out) {
        uint4 pk;
        pk.x = packbf2(r[0], r[1]); pk.y = packbf2(r[2], r[3]);
        pk.z = packbf2(r[4], r[5]); pk.w = packbf2(r[6], r[7]);
        *(uint4*)(a2out + (size_t)v * H + sl * 8) = pk;
      } else {
#pragma unroll
        for (int k = 0; k < 8; k++) cs[k] += r[k];
      }
    }
  }
  if (colsum) {
#pragma unroll
    for (int k = 0; k < 8; k++) {
      float v = cs[k];
      v += __shfl_xor(v, 16);
      v += __shfl_xor(v, 32);
      if (eg == 0) atomicAdd(&cacc[sl * 8 + k], v);
    }
    __syncthreads();
    if (t < 128) atomicAdd(&colsum[t], cacc[t]);
  }
}

// ---------------- Q = sum_v (1/deg_v) * sum_{j in edges(v)} ccnt[j] ----------------
__global__ __launch_bounds__(256) void k_qsum(const int* __restrict__ roff, const int* __restrict__ ridx,
                                              const int* __restrict__ ccnt, float* __restrict__ qsum) {
  __shared__ float red[256];
  int t = threadIdx.x;
  int v = blockIdx.x * 256 + t;
  float q = 0.f;
  if (v < N_V) {
    int o0 = roff[v], n = roff[v + 1] - o0;
    float s = 0.f;
    for (int k = 0; k < n; k++) s += (float)ccnt[ridx[o0 + k]];
    q = (n > 0) ? s / (float)n : 0.f;
  }
  red[t] = q;
  __syncthreads();
  for (int o = 128; o > 0; o >>= 1) {
    if (t < o) red[t] += red[t + o];
    __syncthreads();
  }
  if (t == 0) atomicAdd(qsum, red[0]);
}

// ---------------- final ----------------
__global__ __launch_bounds__(128) void k_final(const float* __restrict__ cAM, const float* __restrict__ cE,
                                               const float* __restrict__ qsum,
                                               const float* __restrict__ Wl1, const float* __restrict__ bl1,
                                               const float* __restrict__ Wo0, const float* __restrict__ bo0,
                                               const float* __restrict__ Wo1, const float* __restrict__ bo1,
                                               float* __restrict__ out) {
  __shared__ float red[128];
  int t = threadIdx.x;
  float sx = 0.f, se = 0.f;
  for (int k = 0; k < H; k++) {
    float w = Wl1[k * H + t];
    sx += cAM[k] * w;
    se += cE[k] * w;
  }
  float Q = qsum[0];
  sx += ((float)N_V + Q) * bl1[t];
  se += (float)NNZ * bl1[t];
  float v = sx * (1.0f / (float)N_V) * Wo0[t] + se * (1.0f / (float)N_E) * Wo1[t];
  red[t] = v;
  __syncthreads();
  for (int o = 64; o > 0; o >>= 1) {
    if (t < o) red[t] += red[t + o];
    __syncthreads();
  }
  if (t == 0) out[0] = red[0] + bo0[0] + bo1[0];
}

extern "C" void kernel_launch(void* const* d_in, const int* in_sizes, int n_in,
                              void* d_out, int out_size, void* d_ws, size_t ws_size,
                              hipStream_t stream) {
  const float* x0in = (const float*)d_in[0];
  const int* rows   = (const int*)d_in[2];
  const int* cols   = (const int*)d_in[3];
  const float* W0   = (const float*)d_in[4];
  const float* b0   = (const float*)d_in[5];
  const float* Wl0  = (const float*)d_in[8];
  const float* bl0  = (const float*)d_in[9];
  const float* Wl1  = (const float*)d_in[10];
  const float* bl1  = (const float*)d_in[11];
  const float* Wo0  = (const float*)d_in[12];
  const float* bo0  = (const float*)d_in[13];
  const float* Wo1  = (const float*)d_in[14];
  const float* bo1  = (const float*)d_in[15];
  float* out = (float*)d_out;
  char* ws = (char*)d_ws;

  int*   rcnt = (int*)(ws + 0);
  int*   ccnt = (int*)(ws + 400000);
  float* csx  = (float*)(ws + 1200000);
  float* cse  = (float*)(ws + 1200512);
  float* qsum = (float*)(ws + 1201024);
  int*   roff = (int*)(ws + 1201152);
  int*   coff = (int*)(ws + 1601280);
  int*   rcur = (int*)(ws + 2401408);
  int*   ccur = (int*)(ws + 2801408);
  int*   ridx = (int*)(ws + 3601408);
  int*   cidx = (int*)(ws + 6801408);
  int*   bsR  = (int*)(ws + 10001408);
  int*   bsC  = (int*)(ws + 10002432);
  int*   gcurR= (int*)(ws + 10003456);
  int*   gcurC= (int*)(ws + 10004480);
  unsigned short* xb = (unsigned short*)(ws + 10005504);
  unsigned short* hb = (unsigned short*)(ws + 35613696);
  unsigned short* eb = (unsigned short*)(ws + 61221888);
  uint2* binnedR = (uint2*)(ws + 35613696);
  uint2* binnedC = (uint2*)(ws + 42013696);

  hipMemsetAsync(ws, 0, 1201028, stream);
  k_hist<<<dim3((NNZ + 255) / 256), dim3(256), 0, stream>>>(rows, cols, rcnt, ccnt);
  k_scan_blk<<<dim3(98),  dim3(256), 0, stream>>>(rcnt, N_V, roff, bsR);
  k_scan_blk<<<dim3(196), dim3(256), 0, stream>>>(ccnt, N_E, coff, bsC);
  k_scan_top<<<dim3(1), dim3(256), 0, stream>>>(bsR, 98);
  k_scan_top<<<dim3(1), dim3(256), 0, stream>>>(bsC, 196);
  k_scan_fix<<<dim3(98),  dim3(256), 0, stream>>>(roff, bsR, N_V, rcur);
  k_scan_fix<<<dim3(196), dim3(256), 0, stream>>>(coff, bsC, N_E, ccur);
  k_binit<<<dim3(1), dim3(256), 0, stream>>>(roff, coff, gcurR, gcurC);
  k_bin<<<dim3(196), dim3(256), 0, stream>>>(rows, cols, 9, 196, gcurR, binnedR);
  k_bin<<<dim3(196), dim3(256), 0, stream>>>(cols, rows, 10, 196, gcurC, binnedC);
  k_fine<<<dim3(196), dim3(256), 0, stream>>>(binnedR, roff, ridx, rcur, 9, N_V);
  k_fine<<<dim3(196), dim3(256), 0, stream>>>(binnedC, coff, cidx, ccur, 10, N_E);

  k_inproj<<<dim3(N_V / 16), dim3(256), 0, stream>>>(x0in, W0, b0, xb);
  k_gemm<<<dim3((N_V + 63) / 64), dim3(256), 0, stream>>>(xb, Wl0, bl0, hb, N_V);   // h1
  k_epass<<<dim3(2048), dim3(256), 0, stream>>>(hb, coff, cidx, eb, nullptr);       // e1
  k_mpass<<<dim3(2048), dim3(256), 0, stream>>>(eb, roff, ridx, hb, xb, nullptr);   // a2 = h1 + m1
  k_epass<<<dim3(2048), dim3(256), 0, stream>>>(xb, coff, cidx, eb, cse);           // Ea = B^T a2, cE
  k_qsum<<<dim3((N_V + 255) / 256), dim3(256), 0, stream>>>(roff, ridx, ccnt, qsum);
  k_mpass<<<dim3(2048), dim3(256), 0, stream>>>(eb, roff, ridx, xb, nullptr, csx);  // colsum(a2 + Ma)
  k_final<<<dim3(1), dim3(128), 0, stream>>>(csx, cse, qsum, Wl1, bl1, Wo0, bo0, Wo1, bo1, out);
}

// Round 4
// 519.118 us; speedup vs baseline: 1.4516x; 1.0390x over previous
//
#include <hip/hip_runtime.h>
#include <stdint.h>

#define N_V 100000
#define N_E 200000
#define NNZ 800000
#define D_IN 14
#define H 128

__device__ __forceinline__ unsigned short f2bf(float f) {
  unsigned int u = __float_as_uint(f);
  u += 0x7fffu + ((u >> 16) & 1u);
  return (unsigned short)(u >> 16);
}
__device__ __forceinline__ float bflo(unsigned int u) { return __uint_as_float(u << 16); }
__device__ __forceinline__ float bfhi(unsigned int u) { return __uint_as_float(u & 0xffff0000u); }
__device__ __forceinline__ unsigned int packbf2(float a, float b) {
  return (unsigned int)f2bf(a) | ((unsigned int)f2bf(b) << 16);
}

// ---------------- CSR build: histogram ----------------
__global__ __launch_bounds__(256) void k_hist(const int* __restrict__ rows, const int* __restrict__ cols,
                                              int* __restrict__ rcnt, int* __restrict__ ccnt) {
  int i = blockIdx.x * 256 + threadIdx.x;
  if (i < NNZ) {
    atomicAdd(&rcnt[rows[i]], 1);
    atomicAdd(&ccnt[cols[i]], 1);
  }
}

__global__ __launch_bounds__(256) void k_invdeg(const int* __restrict__ rcnt, float* __restrict__ invdeg) {
  int v = blockIdx.x * 256 + threadIdx.x;
  if (v < N_V) {
    int n = rcnt[v];
    invdeg[v] = 1.f / (float)(n > 0 ? n : 1);
  }
}

__global__ __launch_bounds__(256) void k_scan_blk(const int* __restrict__ cnt, int n,
                                                  int* __restrict__ off, int* __restrict__ bsum) {
  __shared__ int s[256];
  int t = threadIdx.x;
  int base = blockIdx.x * 1024 + t * 4;
  int v0 = (base + 0 < n) ? cnt[base + 0] : 0;
  int v1 = (base + 1 < n) ? cnt[base + 1] : 0;
  int v2 = (base + 2 < n) ? cnt[base + 2] : 0;
  int v3 = (base + 3 < n) ? cnt[base + 3] : 0;
  int sum = v0 + v1 + v2 + v3;
  s[t] = sum;
  __syncthreads();
  for (int o = 1; o < 256; o <<= 1) {
    int x = (t >= o) ? s[t - o] : 0;
    __syncthreads();
    s[t] += x;
    __syncthreads();
  }
  int excl = s[t] - sum;
  if (base + 0 < n) off[base + 0] = excl;
  if (base + 1 < n) off[base + 1] = excl + v0;
  if (base + 2 < n) off[base + 2] = excl + v0 + v1;
  if (base + 3 < n) off[base + 3] = excl + v0 + v1 + v2;
  if (t == 255) bsum[blockIdx.x] = s[255];
}

__global__ __launch_bounds__(256) void k_scan_top(int* __restrict__ bsum, int nb) {
  __shared__ int s[256];
  int t = threadIdx.x;
  int v = (t < nb) ? bsum[t] : 0;
  s[t] = v;
  __syncthreads();
  for (int o = 1; o < 256; o <<= 1) {
    int x = (t >= o) ? s[t - o] : 0;
    __syncthreads();
    s[t] += x;
    __syncthreads();
  }
  if (t < nb) bsum[t] = s[t] - v;
}

__global__ __launch_bounds__(256) void k_scan_fix(int* __restrict__ off, const int* __restrict__ bsum,
                                                  int n, int* __restrict__ cur) {
  int t = threadIdx.x;
  int add = bsum[blockIdx.x];
  int base = blockIdx.x * 1024 + t * 4;
#pragma unroll
  for (int j = 0; j < 4; j++) {
    int idx = base + j;
    if (idx < n) { int v = off[idx] + add; off[idx] = v; cur[idx] = v; }
  }
  if (blockIdx.x == 0 && t == 0) off[n] = NNZ;
}

__global__ __launch_bounds__(256) void k_binit(const int* __restrict__ roff, const int* __restrict__ coff,
                                               int* __restrict__ gcurR, int* __restrict__ gcurC) {
  int t = threadIdx.x;
  if (t < 196) {
    gcurR[t] = roff[t << 9];
    gcurC[t] = coff[t << 10];
  }
}

// ---------------- binning pass ----------------
__global__ __launch_bounds__(256) void k_bin(const int* __restrict__ keys, const int* __restrict__ vals,
                                             int shift, int nb, int* __restrict__ gcur,
                                             uint2* __restrict__ binned) {
  __shared__ int bcnt[256], bsc[256], bex[256], gb[256];
  __shared__ uint2 recs[4096];
  __shared__ unsigned char bid[4096];
  int t = threadIdx.x;
  bcnt[t] = 0;
  __syncthreads();
  int base = blockIdx.x * 4096;
  int k_[16], v_[16], lp[16];
  short bb[16];
#pragma unroll
  for (int u = 0; u < 16; u++) {
    int i = base + u * 256 + t;
    if (i < NNZ) {
      k_[u] = keys[i]; v_[u] = vals[i];
      int b = k_[u] >> shift;
      bb[u] = (short)b;
      lp[u] = atomicAdd(&bcnt[b], 1);
    } else bb[u] = -1;
  }
  __syncthreads();
  bsc[t] = bcnt[t];
  __syncthreads();
  for (int o = 1; o < 256; o <<= 1) {
    int x = (t >= o) ? bsc[t - o] : 0;
    __syncthreads();
    bsc[t] += x;
    __syncthreads();
  }
  bex[t] = bsc[t] - bcnt[t];
  __syncthreads();
#pragma unroll
  for (int u = 0; u < 16; u++) {
    if (bb[u] >= 0) {
      int p = bex[bb[u]] + lp[u];
      recs[p] = make_uint2((unsigned)k_[u], (unsigned)v_[u]);
      bid[p] = (unsigned char)bb[u];
    }
  }
  if (t < nb && bcnt[t] > 0) gb[t] = atomicAdd(&gcur[t], bcnt[t]);
  __syncthreads();
  int total = bsc[255];
  for (int p = t; p < total; p += 256) {
    int b = bid[p];
    binned[gb[b] + (p - bex[b])] = recs[p];
  }
}

// ---------------- fine pass ----------------
__global__ __launch_bounds__(256) void k_fine(const uint2* __restrict__ binned, const int* __restrict__ off,
                                              int* __restrict__ idx, int* __restrict__ gcurFB,
                                              int shift, int n_keys) {
  __shared__ int cur[1024];
  __shared__ int vals[6144];
  int t = threadIdx.x;
  int kbase = blockIdx.x << shift;
  int kend = kbase + (1 << shift);
  if (kend > n_keys) kend = n_keys;
  int lo = off[kbase], hi = off[kend];
  int cnt = hi - lo;
  for (int r = t; r < kend - kbase; r += 256) cur[r] = off[kbase + r] - lo;
  __syncthreads();
  if (cnt <= 6144) {
    for (int p = t; p < cnt; p += 256) {
      uint2 rec = binned[lo + p];
      int pos = atomicAdd(&cur[(int)rec.x - kbase], 1);
      vals[pos] = (int)rec.y;
    }
    __syncthreads();
    for (int p = t; p < cnt; p += 256) idx[lo + p] = vals[p];
  } else {
    for (int p = t; p < cnt; p += 256) {
      uint2 rec = binned[lo + p];
      int pos = atomicAdd(&gcurFB[rec.x], 1);
      idx[pos] = (int)rec.y;
    }
  }
}

// ---------------- w_j = sum_{v in edge j} invdeg[v];  Q' = sum_j w_j * deg_e(j) ----------------
__global__ __launch_bounds__(256) void k_wsum(const int* __restrict__ coff, const int* __restrict__ cidx,
                                              const float* __restrict__ invdeg,
                                              float* __restrict__ w, float* __restrict__ qsum) {
  __shared__ float red[256];
  int t = threadIdx.x;
  int j = blockIdx.x * 256 + t;
  float q = 0.f;
  if (j < N_E) {
    int o0 = coff[j], n = coff[j + 1] - o0;
    float wj = 0.f;
    for (int s = 0; s < n; s++) wj += invdeg[cidx[o0 + s]];
    w[j] = wj;
    q = wj * (float)n;
  }
  red[t] = q;
  __syncthreads();
  for (int o = 128; o > 0; o >>= 1) {
    if (t < o) red[t] += red[t + o];
    __syncthreads();
  }
  if (t == 0) atomicAdd(qsum, red[0]);
}

// ---------------- fused input weight: W0f = W0 @ Wl0, b0f = b0 @ Wl0 + bl0 ----------------
__global__ __launch_bounds__(128) void k_fusew(const float* __restrict__ W0, const float* __restrict__ b0,
                                               const float* __restrict__ Wl0, const float* __restrict__ bl0,
                                               float* __restrict__ W0f, float* __restrict__ b0f) {
  int n = threadIdx.x;
  for (int d = 0; d < D_IN; d++) {
    float acc = 0.f;
    for (int k = 0; k < H; k++) acc += W0[d * H + k] * Wl0[k * H + n];
    W0f[d * H + n] = acc;
  }
  float accb = bl0[n];
  for (int k = 0; k < H; k++) accb += b0[k] * Wl0[k * H + n];
  b0f[n] = accb;
}

// ---------------- h1 = x_0 @ W0f + b0f  (bf16 out) ----------------
__global__ __launch_bounds__(256) void k_inproj(const float* __restrict__ X, const float* __restrict__ W,
                                                const float* __restrict__ b, unsigned short* __restrict__ out) {
  __shared__ float Ws[D_IN * H];
  __shared__ float Bs[H];
  int t = threadIdx.x;
  for (int i = t; i < D_IN * H; i += 256) Ws[i] = W[i];
  if (t < H) Bs[t] = b[t];
  __syncthreads();
  int row = blockIdx.x * 16 + (t >> 4);
  int cg = (t & 15) * 8;
  float acc[8];
#pragma unroll
  for (int j = 0; j < 8; j++) acc[j] = Bs[cg + j];
#pragma unroll
  for (int k = 0; k < D_IN; k++) {
    float xv = X[row * D_IN + k];
#pragma unroll
    for (int j = 0; j < 8; j++) acc[j] += xv * Ws[k * H + cg + j];
  }
  unsigned int pk0 = packbf2(acc[0], acc[1]);
  unsigned int pk1 = packbf2(acc[2], acc[3]);
  unsigned int pk2 = packbf2(acc[4], acc[5]);
  unsigned int pk3 = packbf2(acc[6], acc[7]);
  *(uint4*)(out + (size_t)row * H + cg) = make_uint4(pk0, pk1, pk2, pk3);
}

// helper: accumulate 8 bf16 (uint4) into 8 floats
#define ACC8(a, u) do { \
  a[0] += bflo((u).x); a[1] += bfhi((u).x); \
  a[2] += bflo((u).y); a[3] += bfhi((u).y); \
  a[4] += bflo((u).z); a[5] += bfhi((u).z); \
  a[6] += bflo((u).w); a[7] += bfhi((u).w); } while (0)

// ---------------- pass 1: e1 = B^T h1  (4 edges/wave, 16 lanes x uint4) ----------------
__global__ __launch_bounds__(256) void k_epass(const unsigned short* __restrict__ h,
                                               const int* __restrict__ coff, const int* __restrict__ cidx,
                                               unsigned short* __restrict__ e) {
  int t = threadIdx.x, lane = t & 63;
  int eg = lane >> 4, sl = lane & 15;
  int gw = blockIdx.x * 4 + (t >> 6);
  int nw = gridDim.x * 4;
  const int NB = (N_E + 3) >> 2;
  for (int b = gw; b < NB; b += nw) {
    int j = b * 4 + eg;
    bool jv = j < N_E;
    int o0 = 0, n = 0;
    if (jv) { o0 = coff[j]; n = coff[j + 1] - o0; }
    float a[8] = {0.f, 0.f, 0.f, 0.f, 0.f, 0.f, 0.f, 0.f};
    int s = 0;
    for (; s + 4 <= n; s += 4) {
      int v0 = cidx[o0 + s], v1 = cidx[o0 + s + 1], v2 = cidx[o0 + s + 2], v3 = cidx[o0 + s + 3];
      uint4 u0 = *(const uint4*)(h + (size_t)v0 * H + sl * 8);
      uint4 u1 = *(const uint4*)(h + (size_t)v1 * H + sl * 8);
      uint4 u2 = *(const uint4*)(h + (size_t)v2 * H + sl * 8);
      uint4 u3 = *(const uint4*)(h + (size_t)v3 * H + sl * 8);
      ACC8(a, u0); ACC8(a, u1); ACC8(a, u2); ACC8(a, u3);
    }
    for (; s < n; ++s) {
      int v = cidx[o0 + s];
      uint4 u = *(const uint4*)(h + (size_t)v * H + sl * 8);
      ACC8(a, u);
    }
    if (jv) {
      uint4 pk;
      pk.x = packbf2(a[0], a[1]); pk.y = packbf2(a[2], a[3]);
      pk.z = packbf2(a[4], a[5]); pk.w = packbf2(a[6], a[7]);
      *(uint4*)(e + (size_t)j * H + sl * 8) = pk;
    }
  }
}

// ---------------- pass 2: a2 = h1 + D^-1 B e1 (in-place on h), colsum(a2 fp32) -> csx ----------------
__global__ __launch_bounds__(256) void k_mpass(const unsigned short* __restrict__ e,
                                               const int* __restrict__ roff, const int* __restrict__ ridx,
                                               unsigned short* h,  // read h1, write a2 in place
                                               float* __restrict__ colsum) {
  __shared__ float cacc[128];
  int t = threadIdx.x, lane = t & 63;
  int eg = lane >> 4, sl = lane & 15;
  if (t < 128) cacc[t] = 0.f;
  __syncthreads();
  int gw = blockIdx.x * 4 + (t >> 6);
  int nw = gridDim.x * 4;
  float cs[8] = {0.f, 0.f, 0.f, 0.f, 0.f, 0.f, 0.f, 0.f};
  const int NB = (N_V + 3) >> 2;
  for (int b = gw; b < NB; b += nw) {
    int v = b * 4 + eg;
    bool vv = v < N_V;
    int o0 = 0, n = 0;
    if (vv) { o0 = roff[v]; n = roff[v + 1] - o0; }
    float a[8] = {0.f, 0.f, 0.f, 0.f, 0.f, 0.f, 0.f, 0.f};
    int s = 0;
    for (; s + 4 <= n; s += 4) {
      int j0 = ridx[o0 + s], j1 = ridx[o0 + s + 1], j2 = ridx[o0 + s + 2], j3 = ridx[o0 + s + 3];
      uint4 u0 = *(const uint4*)(e + (size_t)j0 * H + sl * 8);
      uint4 u1 = *(const uint4*)(e + (size_t)j1 * H + sl * 8);
      uint4 u2 = *(const uint4*)(e + (size_t)j2 * H + sl * 8);
      uint4 u3 = *(const uint4*)(e + (size_t)j3 * H + sl * 8);
      ACC8(a, u0); ACC8(a, u1); ACC8(a, u2); ACC8(a, u3);
    }
    for (; s < n; ++s) {
      int j = ridx[o0 + s];
      uint4 u = *(const uint4*)(e + (size_t)j * H + sl * 8);
      ACC8(a, u);
    }
    if (vv) {
      float inv = (n > 0) ? (1.f / (float)n) : 1.f;
      uint4 uh = *(const uint4*)(h + (size_t)v * H + sl * 8);
      float r[8];
      r[0] = bflo(uh.x) + a[0] * inv; r[1] = bfhi(uh.x) + a[1] * inv;
      r[2] = bflo(uh.y) + a[2] * inv; r[3] = bfhi(uh.y) + a[3] * inv;
      r[4] = bflo(uh.z) + a[4] * inv; r[5] = bfhi(uh.z) + a[5] * inv;
      r[6] = bflo(uh.w) + a[6] * inv; r[7] = bfhi(uh.w) + a[7] * inv;
      uint4 pk;
      pk.x = packbf2(r[0], r[1]); pk.y = packbf2(r[2], r[3]);
      pk.z = packbf2(r[4], r[5]); pk.w = packbf2(r[6], r[7]);
      *(uint4*)(h + (size_t)v * H + sl * 8) = pk;
#pragma unroll
      for (int k = 0; k < 8; k++) cs[k] += r[k];
    }
  }
#pragma unroll
  for (int k = 0; k < 8; k++) {
    float v = cs[k];
    v += __shfl_xor(v, 16);
    v += __shfl_xor(v, 32);
    if (eg == 0) atomicAdd(&cacc[sl * 8 + k], v);
  }
  __syncthreads();
  if (t < 128) atomicAdd(&colsum[t], cacc[t]);
}

// ---------------- pass 3: Ea rows (not stored): csE += row, csW += w_j * row ----------------
__global__ __launch_bounds__(256) void k_efin(const unsigned short* __restrict__ h,
                                              const int* __restrict__ coff, const int* __restrict__ cidx,
                                              const float* __restrict__ w,
                                              float* __restrict__ csE, float* __restrict__ csW) {
  __shared__ float caccE[128], caccW[128];
  int t = threadIdx.x, lane = t & 63;
  int eg = lane >> 4, sl = lane & 15;
  if (t < 128) { caccE[t] = 0.f; caccW[t] = 0.f; }
  __syncthreads();
  int gw = blockIdx.x * 4 + (t >> 6);
  int nw = gridDim.x * 4;
  float ce[8] = {0.f, 0.f, 0.f, 0.f, 0.f, 0.f, 0.f, 0.f};
  float cw[8] = {0.f, 0.f, 0.f, 0.f, 0.f, 0.f, 0.f, 0.f};
  const int NB = (N_E + 3) >> 2;
  for (int b = gw; b < NB; b += nw) {
    int j = b * 4 + eg;
    bool jv = j < N_E;
    int o0 = 0, n = 0;
    float wj = 0.f;
    if (jv) { o0 = coff[j]; n = coff[j + 1] - o0; wj = w[j]; }
    float a[8] = {0.f, 0.f, 0.f, 0.f, 0.f, 0.f, 0.f, 0.f};
    int s = 0;
    for (; s + 4 <= n; s += 4) {
      int v0 = cidx[o0 + s], v1 = cidx[o0 + s + 1], v2 = cidx[o0 + s + 2], v3 = cidx[o0 + s + 3];
      uint4 u0 = *(const uint4*)(h + (size_t)v0 * H + sl * 8);
      uint4 u1 = *(const uint4*)(h + (size_t)v1 * H + sl * 8);
      uint4 u2 = *(const uint4*)(h + (size_t)v2 * H + sl * 8);
      uint4 u3 = *(const uint4*)(h + (size_t)v3 * H + sl * 8);
      ACC8(a, u0); ACC8(a, u1); ACC8(a, u2); ACC8(a, u3);
    }
    for (; s < n; ++s) {
      int v = cidx[o0 + s];
      uint4 u = *(const uint4*)(h + (size_t)v * H + sl * 8);
      ACC8(a, u);
    }
    if (jv) {
#pragma unroll
      for (int k = 0; k < 8; k++) { ce[k] += a[k]; cw[k] += wj * a[k]; }
    }
  }
#pragma unroll
  for (int k = 0; k < 8; k++) {
    float ve = ce[k], vw = cw[k];
    ve += __shfl_xor(ve, 16); ve += __shfl_xor(ve, 32);
    vw += __shfl_xor(vw, 16); vw += __shfl_xor(vw, 32);
    if (eg == 0) { atomicAdd(&caccE[sl * 8 + k], ve); atomicAdd(&caccW[sl * 8 + k], vw); }
  }
  __syncthreads();
  if (t < 128) { atomicAdd(&csE[t], caccE[t]); atomicAdd(&csW[t], caccW[t]); }
}

// ---------------- final ----------------
__global__ __launch_bounds__(128) void k_final(const float* __restrict__ csx, const float* __restrict__ csW,
                                               const float* __restrict__ csE, const float* __restrict__ qsum,
                                               const float* __restrict__ Wl1, const float* __restrict__ bl1,
                                               const float* __restrict__ Wo0, const float* __restrict__ bo0,
                                               const float* __restrict__ Wo1, const float* __restrict__ bo1,
                                               float* __restrict__ out) {
  __shared__ float red[128];
  int t = threadIdx.x;
  float sx = 0.f, se = 0.f;
  for (int k = 0; k < H; k++) {
    float wv = Wl1[k * H + t];
    sx += (csx[k] + csW[k]) * wv;
    se += csE[k] * wv;
  }
  float Q = qsum[0];
  sx += ((float)N_V + Q) * bl1[t];
  se += (float)NNZ * bl1[t];
  float v = sx * (1.0f / (float)N_V) * Wo0[t] + se * (1.0f / (float)N_E) * Wo1[t];
  red[t] = v;
  __syncthreads();
  for (int o = 64; o > 0; o >>= 1) {
    if (t < o) red[t] += red[t + o];
    __syncthreads();
  }
  if (t == 0) out[0] = red[0] + bo0[0] + bo1[0];
}

extern "C" void kernel_launch(void* const* d_in, const int* in_sizes, int n_in,
                              void* d_out, int out_size, void* d_ws, size_t ws_size,
                              hipStream_t stream) {
  const float* x0in = (const float*)d_in[0];
  const int* rows   = (const int*)d_in[2];
  const int* cols   = (const int*)d_in[3];
  const float* W0   = (const float*)d_in[4];
  const float* b0   = (const float*)d_in[5];
  const float* Wl0  = (const float*)d_in[8];
  const float* bl0  = (const float*)d_in[9];
  const float* Wl1  = (const float*)d_in[10];
  const float* bl1  = (const float*)d_in[11];
  const float* Wo0  = (const float*)d_in[12];
  const float* bo0  = (const float*)d_in[13];
  const float* Wo1  = (const float*)d_in[14];
  const float* bo1  = (const float*)d_in[15];
  float* out = (float*)d_out;
  char* ws = (char*)d_ws;

  // workspace layout
  int*   rcnt  = (int*)(ws + 0);              //   400000
  int*   ccnt  = (int*)(ws + 400000);         //   800000
  float* csx   = (float*)(ws + 1200000);      //      512   colsum(a2)
  float* csE   = (float*)(ws + 1200512);      //      512   colsum(Ea)
  float* csW   = (float*)(ws + 1201024);      //      512   weighted colsum(Ea)
  float* qsum  = (float*)(ws + 1201536);      //        4   Q'   -> zero [0, 1201540)
  int*   roff  = (int*)(ws + 1201664);        //   400004
  int*   coff  = (int*)(ws + 1601792);        //   800004
  int*   rcur  = (int*)(ws + 2401920);        //   400000
  int*   ccur  = (int*)(ws + 2801920);        //   800000
  int*   ridx  = (int*)(ws + 3601920);        //  3200000
  int*   cidx  = (int*)(ws + 6801920);        //  3200000
  int*   bsR   = (int*)(ws + 10001920);       //     1024
  int*   bsC   = (int*)(ws + 10002944);       //     1024
  int*   gcurR = (int*)(ws + 10003968);       //     1024
  int*   gcurC = (int*)(ws + 10004992);       //     1024
  float* invdg = (float*)(ws + 10006016);     //   400000
  float* wbuf  = (float*)(ws + 10406016);     //   800000
  float* W0f   = (float*)(ws + 11206016);     //     7168
  float* b0f   = (float*)(ws + 11213184);     //      512
  unsigned short* hb = (unsigned short*)(ws + 11213696);  // 25600000 (h1, then a2 in-place)
  unsigned short* eb = (unsigned short*)(ws + 36813696);  // 51200000 (e1)
  // binned temps alias hb region (consumed by k_fine before k_inproj writes hb)
  uint2* binnedR = (uint2*)(ws + 11213696);               // 6400000
  uint2* binnedC = (uint2*)(ws + 17613696);               // 6400000
  // total: 88013696 B

  hipMemsetAsync(ws, 0, 1201540, stream);
  k_hist<<<dim3((NNZ + 255) / 256), dim3(256), 0, stream>>>(rows, cols, rcnt, ccnt);
  k_invdeg<<<dim3((N_V + 255) / 256), dim3(256), 0, stream>>>(rcnt, invdg);
  k_scan_blk<<<dim3(98),  dim3(256), 0, stream>>>(rcnt, N_V, roff, bsR);
  k_scan_blk<<<dim3(196), dim3(256), 0, stream>>>(ccnt, N_E, coff, bsC);
  k_scan_top<<<dim3(1), dim3(256), 0, stream>>>(bsR, 98);
  k_scan_top<<<dim3(1), dim3(256), 0, stream>>>(bsC, 196);
  k_scan_fix<<<dim3(98),  dim3(256), 0, stream>>>(roff, bsR, N_V, rcur);
  k_scan_fix<<<dim3(196), dim3(256), 0, stream>>>(coff, bsC, N_E, ccur);
  k_binit<<<dim3(1), dim3(256), 0, stream>>>(roff, coff, gcurR, gcurC);
  k_bin<<<dim3(196), dim3(256), 0, stream>>>(rows, cols, 9, 196, gcurR, binnedR);
  k_bin<<<dim3(196), dim3(256), 0, stream>>>(cols, rows, 10, 196, gcurC, binnedC);
  k_fine<<<dim3(196), dim3(256), 0, stream>>>(binnedR, roff, ridx, rcur, 9, N_V);
  k_fine<<<dim3(196), dim3(256), 0, stream>>>(binnedC, coff, cidx, ccur, 10, N_E);
  k_wsum<<<dim3((N_E + 255) / 256), dim3(256), 0, stream>>>(coff, cidx, invdg, wbuf, qsum);

  k_fusew<<<dim3(1), dim3(128), 0, stream>>>(W0, b0, Wl0, bl0, W0f, b0f);
  k_inproj<<<dim3(N_V / 16), dim3(256), 0, stream>>>(x0in, W0f, b0f, hb);          // h1
  k_epass<<<dim3(2048), dim3(256), 0, stream>>>(hb, coff, cidx, eb);               // e1 = B^T h1
  k_mpass<<<dim3(2048), dim3(256), 0, stream>>>(eb, roff, ridx, hb, csx);          // a2 in-place + csx
  k_efin<<<dim3(2048), dim3(256), 0, stream>>>(hb, coff, cidx, wbuf, csE, csW);    // csE, csW
  k_final<<<dim3(1), dim3(128), 0, stream>>>(csx, csW, csE, qsum, Wl1, bl1, Wo0, bo0, Wo1, bo1, out);
}